// Round 2
// baseline (807.542 us; speedup 1.0000x reference)
//
#include <hip/hip_runtime.h>

#define M_ACT 4000
#define NE 150000
#define NT 586   // ceil(NE/256)
#define DD 128

#define ASTR 136   // actor LDS row stride (shorts), mult of 8 for b128 alignment
#define WSTR 72    // wblob chunk row stride (shorts)

typedef __attribute__((ext_vector_type(8))) short bh8;
typedef __attribute__((ext_vector_type(4))) float vf4;

#define MFMA16(a, b, c) __builtin_amdgcn_mfma_f32_16x16x32_bf16((a), (b), (c), 0, 0, 0)

__device__ __forceinline__ unsigned short f2bf(float f) {
    unsigned u = __float_as_uint(f);
    u = (u + 0x7fffu + ((u >> 16) & 1u)) >> 16;
    return (unsigned short)u;
}
__device__ __forceinline__ float bf2f(unsigned short s) {
    return __uint_as_float(((unsigned)s) << 16);
}

// GroupNorm stats from one 16x128 MFMA C-layout row-tile (acc[8] col-tiles).
// Row r = grp*4+i is held by the 16 lanes sharing grp -> reduce over lm only.
__device__ __forceinline__ void gn_stats8(const vf4* acc, float* mean, float* rs) {
    float s[4], q[4];
#pragma unroll
    for (int i = 0; i < 4; i++) {
        float a = 0.f, b = 0.f;
#pragma unroll
        for (int t = 0; t < 8; t++) { float v = acc[t][i]; a += v; b += v * v; }
        s[i] = a; q[i] = b;
    }
#pragma unroll
    for (int m = 1; m < 16; m <<= 1) {
#pragma unroll
        for (int i = 0; i < 4; i++) {
            s[i] += __shfl_xor(s[i], m, 64);
            q[i] += __shfl_xor(q[i], m, 64);
        }
    }
#pragma unroll
    for (int i = 0; i < 4; i++) {
        float mu = s[i] * (1.0f / 128.0f);
        float var = q[i] * (1.0f / 128.0f) - mu * mu;
        mean[i] = mu;
        rs[i] = rsqrtf(var + 1e-5f);
    }
}

template <bool RELU>
__device__ __forceinline__ void gn_to_lds(const vf4* acc, const float* __restrict__ gw,
                                          const float* __restrict__ gb, unsigned short* sm,
                                          int stride, int cb, int r0, int grp, int lm) {
    float mean[4], rs[4];
    gn_stats8(acc, mean, rs);
#pragma unroll
    for (int t = 0; t < 8; t++) {
        int c = 16 * t + lm;
        float w = gw[c], b = gb[c];
#pragma unroll
        for (int i = 0; i < 4; i++) {
            float y = (acc[t][i] - mean[i]) * rs[i] * w + b;
            if (RELU) y = fmaxf(y, 0.0f);
            sm[(r0 + grp * 4 + i) * stride + cb + c] = f2bf(y);
        }
    }
}

__device__ __forceinline__ void load_chunk(const unsigned short* __restrict__ src,
                                           unsigned short* dst, int tid) {
    for (int idx = tid; idx < 1152; idx += 256) {
        *(uint4*)&dst[idx * 8] = *(const uint4*)&src[idx * 8];
    }
}

// =====================  d0 = relu(ctr_d @ Wd1^T + b)  =====================
__global__ __launch_bounds__(256) void d0_kernel(const float* __restrict__ actor_ctrs,
                                                 const float* __restrict__ node_ctrs,
                                                 const int* __restrict__ hi,
                                                 const int* __restrict__ wi,
                                                 const float* __restrict__ Wd1,
                                                 const float* __restrict__ bd1,
                                                 unsigned short* __restrict__ d0) {
    int gid = blockIdx.x * 256 + threadIdx.x;
    int e = gid >> 5;
    if (e >= NE) return;
    int c0 = (gid & 31) * 4;
    int h = hi[e], w = wi[e];
    float cx = actor_ctrs[h * 2 + 0] - node_ctrs[w * 2 + 0];
    float cy = actor_ctrs[h * 2 + 1] - node_ctrs[w * 2 + 1];
    unsigned short r[4];
#pragma unroll
    for (int j = 0; j < 4; j++) {
        int c = c0 + j;
        float v = fmaf(cy, Wd1[c * 2 + 1], fmaf(cx, Wd1[c * 2 + 0], bd1[c]));
        r[j] = f2bf(fmaxf(v, 0.f));
    }
    unsigned lo = (unsigned)r[0] | ((unsigned)r[1] << 16);
    unsigned hi2 = (unsigned)r[2] | ((unsigned)r[3] << 16);
    *(uint2*)&d0[(size_t)e * DD + c0] = make_uint2(lo, hi2);
}

// =====================  E1: d = relu(gn(d0@Wd2^T)), q = relu(gn(agts[hi]@Wq^T))
// Persistent; Wd2+Wq resident in LDS; wave owns 64 rows (4 row-tiles) so each
// B-read feeds 4 MFMAs.
__global__ __launch_bounds__(256, 2) void e1_kernel(
    const float* __restrict__ agts, const unsigned short* __restrict__ d0,
    const float* __restrict__ Wd2f, const float* __restrict__ Wqf,
    const float* __restrict__ gnd2_w, const float* __restrict__ gnd2_b,
    const float* __restrict__ gnq_w, const float* __restrict__ gnq_b,
    const int* __restrict__ hi, unsigned short* __restrict__ dq,
    int* __restrict__ ctr) {
    __shared__ unsigned short smW[2 * 128 * 136];
    __shared__ int smTile;
    // one-time weight load: f32 -> bf16 LDS [n][k] stride 136
    for (int idx = threadIdx.x; idx < 8192; idx += 256) {
        int m = idx >> 12, rem = idx & 4095;
        int n = rem >> 5, k4 = (rem & 31) << 2;
        const float* src = (m ? Wqf : Wd2f) + n * 128 + k4;
        float4 v = *(const float4*)src;
        unsigned short* d = &smW[m * 17408 + n * 136 + k4];
        *(unsigned*)d = (unsigned)f2bf(v.x) | ((unsigned)f2bf(v.y) << 16);
        *(unsigned*)(d + 2) = (unsigned)f2bf(v.z) | ((unsigned)f2bf(v.w) << 16);
    }
    const int wave = threadIdx.x >> 6, lane = threadIdx.x & 63;
    const int grp = lane >> 4, lm = lane & 15;
    while (true) {
        __syncthreads();
        if (threadIdx.x == 0) smTile = atomicAdd(ctr, 1);
        __syncthreads();
        int tile = smTile;
        if (tile >= NT) break;
        int base = tile * 256 + wave * 64;
        int ra[4], hq[4];
#pragma unroll
        for (int rt = 0; rt < 4; rt++) {
            int r = base + rt * 16 + lm;
            if (r > NE - 1) r = NE - 1;
            ra[rt] = r;
            hq[rt] = hi[r];
        }
        vf4 acc[4][8];
        // ---- d GEMM
#pragma unroll
        for (int rt = 0; rt < 4; rt++)
#pragma unroll
            for (int t = 0; t < 8; t++) acc[rt][t] = (vf4){0.f, 0.f, 0.f, 0.f};
#pragma unroll
        for (int ks = 0; ks < 4; ks++) {
            bh8 B[8];
#pragma unroll
            for (int t = 0; t < 8; t++)
                B[t] = *(const bh8*)&smW[(16 * t + lm) * 136 + ks * 32 + grp * 8];
#pragma unroll
            for (int rt = 0; rt < 4; rt++) {
                bh8 a = *(const bh8*)&d0[(size_t)ra[rt] * DD + ks * 32 + grp * 8];
#pragma unroll
                for (int t = 0; t < 8; t++) acc[rt][t] = MFMA16(a, B[t], acc[rt][t]);
            }
        }
#pragma unroll
        for (int rt = 0; rt < 4; rt++) {
            float mean[4], rs[4];
            gn_stats8(acc[rt], mean, rs);
#pragma unroll
            for (int t = 0; t < 8; t++) {
                int c = 16 * t + lm;
                float w = gnd2_w[c], b = gnd2_b[c];
#pragma unroll
                for (int i = 0; i < 4; i++) {
                    int row = base + rt * 16 + grp * 4 + i;
                    if (row < NE) {
                        float y = (acc[rt][t][i] - mean[i]) * rs[i] * w + b;
                        dq[(size_t)row * 256 + c] = f2bf(fmaxf(y, 0.f));
                    }
                }
            }
        }
        // ---- q GEMM
#pragma unroll
        for (int rt = 0; rt < 4; rt++)
#pragma unroll
            for (int t = 0; t < 8; t++) acc[rt][t] = (vf4){0.f, 0.f, 0.f, 0.f};
#pragma unroll
        for (int ks = 0; ks < 4; ks++) {
            bh8 B[8];
#pragma unroll
            for (int t = 0; t < 8; t++)
                B[t] = *(const bh8*)&smW[17408 + (16 * t + lm) * 136 + ks * 32 + grp * 8];
#pragma unroll
            for (int rt = 0; rt < 4; rt++) {
                const float* ap = agts + (size_t)hq[rt] * DD + ks * 32 + grp * 8;
                float4 v0 = *(const float4*)ap;
                float4 v1 = *(const float4*)(ap + 4);
                bh8 a;
                a[0] = (short)f2bf(v0.x); a[1] = (short)f2bf(v0.y);
                a[2] = (short)f2bf(v0.z); a[3] = (short)f2bf(v0.w);
                a[4] = (short)f2bf(v1.x); a[5] = (short)f2bf(v1.y);
                a[6] = (short)f2bf(v1.z); a[7] = (short)f2bf(v1.w);
#pragma unroll
                for (int t = 0; t < 8; t++) acc[rt][t] = MFMA16(a, B[t], acc[rt][t]);
            }
        }
#pragma unroll
        for (int rt = 0; rt < 4; rt++) {
            float mean[4], rs[4];
            gn_stats8(acc[rt], mean, rs);
#pragma unroll
            for (int t = 0; t < 8; t++) {
                int c = 16 * t + lm;
                float w = gnq_w[c], b = gnq_b[c];
#pragma unroll
                for (int i = 0; i < 4; i++) {
                    int row = base + rt * 16 + grp * 4 + i;
                    if (row < NE) {
                        float y = (acc[rt][t][i] - mean[i]) * rs[i] * w + b;
                        dq[(size_t)row * 256 + 128 + c] = f2bf(fmaxf(y, 0.f));
                    }
                }
            }
        }
    }
}

// =====================  E2: cf1 = relu(gn([d|q|nodes[wi]]@Wc1^T)); cf2 = cf1@Wc2^T
// Persistent; Wc1 resident in LDS; Wc2 B-frags streamed from hot L2 blob;
// cf1 transposed through per-wave LDS buffer (within-wave only, no barrier).
__global__ __launch_bounds__(256, 1) void e2_kernel(
    const unsigned short* __restrict__ dq, const float* __restrict__ nodes,
    const int* __restrict__ wi, const float* __restrict__ Wc1f,
    const unsigned short* __restrict__ w2blob,
    const float* __restrict__ gnc1_w, const float* __restrict__ gnc1_b,
    const int* __restrict__ rank, unsigned short* __restrict__ cf2,
    int* __restrict__ ctr) {
    __shared__ unsigned short smW[128 * 392];
    __shared__ unsigned short smBuf[4][32 * 136];
    __shared__ int smTile;
    for (int idx = threadIdx.x; idx < 12288; idx += 256) {
        int n = idx / 96, k4 = (idx - n * 96) << 2;
        float4 v = *(const float4*)(Wc1f + n * 384 + k4);
        unsigned short* d = &smW[n * 392 + k4];
        *(unsigned*)d = (unsigned)f2bf(v.x) | ((unsigned)f2bf(v.y) << 16);
        *(unsigned*)(d + 2) = (unsigned)f2bf(v.z) | ((unsigned)f2bf(v.w) << 16);
    }
    const int wave = threadIdx.x >> 6, lane = threadIdx.x & 63;
    const int grp = lane >> 4, lm = lane & 15;
    while (true) {
        __syncthreads();
        if (threadIdx.x == 0) smTile = atomicAdd(ctr, 1);
        __syncthreads();
        int tile = smTile;
        if (tile >= NT) break;
        int base = tile * 256 + wave * 64;
        int ra[4], wr[4];
#pragma unroll
        for (int rt = 0; rt < 4; rt++) {
            int r = base + rt * 16 + lm;
            if (r > NE - 1) r = NE - 1;
            ra[rt] = r;
            wr[rt] = wi[r];
        }
        vf4 acc[4][8];
#pragma unroll
        for (int rt = 0; rt < 4; rt++)
#pragma unroll
            for (int t = 0; t < 8; t++) acc[rt][t] = (vf4){0.f, 0.f, 0.f, 0.f};
#pragma unroll 4
        for (int ks = 0; ks < 12; ks++) {
            bh8 B[8];
#pragma unroll
            for (int t = 0; t < 8; t++)
                B[t] = *(const bh8*)&smW[(16 * t + lm) * 392 + ks * 32 + grp * 8];
#pragma unroll
            for (int rt = 0; rt < 4; rt++) {
                bh8 a;
                if (ks < 8) {
                    a = *(const bh8*)&dq[(size_t)ra[rt] * 256 + ks * 32 + grp * 8];
                } else {
                    const float* np = nodes + (size_t)wr[rt] * DD + (ks - 8) * 32 + grp * 8;
                    float4 v0 = *(const float4*)np;
                    float4 v1 = *(const float4*)(np + 4);
                    a[0] = (short)f2bf(v0.x); a[1] = (short)f2bf(v0.y);
                    a[2] = (short)f2bf(v0.z); a[3] = (short)f2bf(v0.w);
                    a[4] = (short)f2bf(v1.x); a[5] = (short)f2bf(v1.y);
                    a[6] = (short)f2bf(v1.z); a[7] = (short)f2bf(v1.w);
                }
#pragma unroll
                for (int t = 0; t < 8; t++) acc[rt][t] = MFMA16(a, B[t], acc[rt][t]);
            }
        }
        // c2 in two halves through the per-wave transpose buffer
#pragma unroll
        for (int half = 0; half < 2; half++) {
            __asm__ volatile("s_waitcnt lgkmcnt(0)" ::: "memory");
#pragma unroll
            for (int r2 = 0; r2 < 2; r2++) {
                int rt = half * 2 + r2;
                float mean[4], rs[4];
                gn_stats8(acc[rt], mean, rs);
#pragma unroll
                for (int t = 0; t < 8; t++) {
                    int c = 16 * t + lm;
                    float w = gnc1_w[c], b = gnc1_b[c];
#pragma unroll
                    for (int i = 0; i < 4; i++) {
                        float y = (acc[rt][t][i] - mean[i]) * rs[i] * w + b;
                        smBuf[wave][(r2 * 16 + grp * 4 + i) * 136 + c] = f2bf(fmaxf(y, 0.f));
                    }
                }
            }
            __asm__ volatile("s_waitcnt lgkmcnt(0)" ::: "memory");
            vf4 acc2[2][8];
#pragma unroll
            for (int r2 = 0; r2 < 2; r2++)
#pragma unroll
                for (int t = 0; t < 8; t++) acc2[r2][t] = (vf4){0.f, 0.f, 0.f, 0.f};
#pragma unroll
            for (int ks = 0; ks < 4; ks++) {
                bh8 B2[8];
#pragma unroll
                for (int t = 0; t < 8; t++)
                    B2[t] = *(const bh8*)&w2blob[(ks >> 1) * 9216 + (16 * t + lm) * WSTR +
                                                 (ks & 1) * 32 + grp * 8];
#pragma unroll
                for (int r2 = 0; r2 < 2; r2++) {
                    bh8 a = *(const bh8*)&smBuf[wave][(r2 * 16 + lm) * 136 + ks * 32 + grp * 8];
#pragma unroll
                    for (int t = 0; t < 8; t++) acc2[r2][t] = MFMA16(a, B2[t], acc2[r2][t]);
                }
            }
#pragma unroll
            for (int r2 = 0; r2 < 2; r2++) {
#pragma unroll
                for (int i = 0; i < 4; i++) {
                    int row = base + (half * 2 + r2) * 16 + grp * 4 + i;
                    if (row < NE) {
                        int rr = rank[row];
                        unsigned short* dst = cf2 + (size_t)rr * DD;
#pragma unroll
                        for (int t = 0; t < 8; t++) dst[16 * t + lm] = f2bf(acc2[r2][t][i]);
                    }
                }
            }
        }
    }
}

// =====================  SEGMENTED SUM (contiguous, rank-permuted cf2)  ==========
__global__ __launch_bounds__(256) void ssum_kernel(const unsigned short* __restrict__ cf2,
                                                   const int* __restrict__ offs,
                                                   float* __restrict__ ssum) {
    int wid = (blockIdx.x * 256 + threadIdx.x) >> 6;
    int lane = threadIdx.x & 63;
    if (wid >= M_ACT) return;
    float s0 = 0.f, s1 = 0.f;
    int j1 = offs[wid + 1];
    for (int j = offs[wid]; j < j1; j++) {
        unsigned u = *(const unsigned*)&cf2[(size_t)j * DD + lane * 2];
        s0 += bf2f((unsigned short)(u & 0xffffu));
        s1 += bf2f((unsigned short)(u >> 16));
    }
    *(float2*)&ssum[(size_t)wid * DD + lane * 2] = make_float2(s0, s1);
}

// =====================  ACTOR KERNEL (unchanged from R1)  =====================
__global__ __launch_bounds__(256, 2) void actor_kernel(
    const float* __restrict__ agts, const float* __restrict__ ssum,
    const float* __restrict__ gnn_w, const float* __restrict__ gnn_b,
    const float* __restrict__ gnl_w, const float* __restrict__ gnl_b,
    const unsigned short* __restrict__ wblob, float* __restrict__ dst) {
    __shared__ unsigned short smA[64 * ASTR];
    __shared__ unsigned short smW[128 * WSTR];
    const int tid = threadIdx.x;
    const int wave = tid >> 6, lane = tid & 63, grp = lane >> 4, lm = lane & 15;
    const int m0 = blockIdx.x * 64;
    const int r0 = wave * 16;
    const int arow = r0 + lm;

    for (int idx = tid; idx < 64 * 32; idx += 256) {
        int r = idx >> 5, q = idx & 31;
        int m = m0 + r;
        if (m >= M_ACT) m = 0;
        const float4 v = *(const float4*)(agts + (size_t)m * DD + q * 4);
        unsigned lo = (unsigned)f2bf(v.x) | ((unsigned)f2bf(v.y) << 16);
        unsigned hi2 = (unsigned)f2bf(v.z) | ((unsigned)f2bf(v.w) << 16);
        *(uint2*)&smA[r * ASTR + q * 4] = make_uint2(lo, hi2);
    }
    __syncthreads();

    vf4 acc[8];
#pragma unroll
    for (int t = 0; t < 8; t++) acc[t] = (vf4){0.f, 0.f, 0.f, 0.f};
    for (int ch = 0; ch < 2; ch++) {
        load_chunk(wblob + (12 + ch) * 9216, smW, tid);
        __syncthreads();
#pragma unroll
        for (int k0 = 0; k0 < 64; k0 += 32) {
            bh8 a = *(const bh8*)&smA[arow * ASTR + ch * 64 + k0 + grp * 8];
#pragma unroll
            for (int t = 0; t < 8; t++) {
                bh8 b = *(const bh8*)&smW[(16 * t + lm) * WSTR + k0 + grp * 8];
                acc[t] = MFMA16(a, b, acc[t]);
            }
        }
        __syncthreads();
    }
#pragma unroll
    for (int t = 0; t < 8; t++) {
#pragma unroll
        for (int i = 0; i < 4; i++) {
            int m = m0 + r0 + grp * 4 + i;
            if (m < M_ACT) acc[t][i] += ssum[(size_t)m * DD + 16 * t + lm];
        }
    }
    gn_to_lds<true>(acc, gnn_w, gnn_b, smA, ASTR, 0, r0, grp, lm);

#pragma unroll
    for (int t = 0; t < 8; t++) acc[t] = (vf4){0.f, 0.f, 0.f, 0.f};
    for (int ch = 0; ch < 2; ch++) {
        load_chunk(wblob + (14 + ch) * 9216, smW, tid);
        __syncthreads();
#pragma unroll
        for (int k0 = 0; k0 < 64; k0 += 32) {
            bh8 a = *(const bh8*)&smA[arow * ASTR + ch * 64 + k0 + grp * 8];
#pragma unroll
            for (int t = 0; t < 8; t++) {
                bh8 b = *(const bh8*)&smW[(16 * t + lm) * WSTR + k0 + grp * 8];
                acc[t] = MFMA16(a, b, acc[t]);
            }
        }
        __syncthreads();
    }
    {
        float mean[4], rs[4];
        gn_stats8(acc, mean, rs);
#pragma unroll
        for (int t = 0; t < 8; t++) {
            int c = 16 * t + lm;
            float w = gnl_w[c], b = gnl_b[c];
#pragma unroll
            for (int i = 0; i < 4; i++) {
                int m = m0 + r0 + grp * 4 + i;
                if (m < M_ACT) {
                    float y = (acc[t][i] - mean[i]) * rs[i] * w + b;
                    y += agts[(size_t)m * DD + c];
                    dst[(size_t)m * DD + c] = fmaxf(y, 0.f);
                }
            }
        }
    }
}

// =====================  SETUP KERNELS  =====================
__global__ void hist_kernel(const int* __restrict__ hi, int* __restrict__ hist) {
    int e = blockIdx.x * 256 + threadIdx.x;
    if (e < NE) atomicAdd(&hist[hi[e]], 1);
}

__global__ void scan_kernel(const int* __restrict__ hist, int* __restrict__ offs,
                            int* __restrict__ cursor) {
    __shared__ int part[256];
    int t = threadIdx.x;
    int base = t * 16;
    int s = 0;
    if (base < M_ACT)
        for (int i = 0; i < 16; i++) s += hist[base + i];
    part[t] = s;
    __syncthreads();
    for (int d = 1; d < 256; d <<= 1) {
        int u = (t >= d) ? part[t - d] : 0;
        __syncthreads();
        part[t] += u;
        __syncthreads();
    }
    int excl = part[t] - s;
    if (base < M_ACT) {
        int run = excl;
        for (int i = 0; i < 16; i++) {
            offs[base + i] = run;
            cursor[base + i] = run;
            run += hist[base + i];
        }
        if (base + 16 == M_ACT) offs[M_ACT] = run;
    }
}

__global__ void scatter_kernel(const int* __restrict__ hi, int* __restrict__ cursor,
                               int* __restrict__ rank) {
    int e = blockIdx.x * 256 + threadIdx.x;
    if (e < NE) rank[e] = atomicAdd(&cursor[hi[e]], 1);
}

__global__ void convert_kernel(const float* __restrict__ Wd2, const float* __restrict__ Wq,
                               const float* __restrict__ Wc1, const float* __restrict__ Wc2,
                               const float* __restrict__ Wa, const float* __restrict__ Wl,
                               unsigned short* __restrict__ wblob) {
    int ci = blockIdx.x;  // 0..31
    int l = ci >> 4, r = ci & 15;
    const float* src;
    int kc, K;
    if (r < 2)       { src = Wd2 + l * 16384; kc = r;      K = 128; }
    else if (r < 4)  { src = Wq  + l * 16384; kc = r - 2;  K = 128; }
    else if (r < 10) { src = Wc1 + l * 49152; kc = r - 4;  K = 384; }
    else if (r < 12) { src = Wc2 + l * 16384; kc = r - 10; K = 128; }
    else if (r < 14) { src = Wa  + l * 16384; kc = r - 12; K = 128; }
    else             { src = Wl  + l * 16384; kc = r - 14; K = 128; }
    unsigned short* dst = wblob + (size_t)ci * 9216;
    for (int idx = threadIdx.x; idx < 9216; idx += 256) {
        int n = idx / 72, kk = idx - n * 72;
        float v = (kk < 64) ? src[n * K + kc * 64 + kk] : 0.f;
        dst[idx] = f2bf(v);
    }
}

extern "C" void kernel_launch(void* const* d_in, const int* in_sizes, int n_in,
                              void* d_out, int out_size, void* d_ws, size_t ws_size,
                              hipStream_t stream) {
    const float* actors = (const float*)d_in[0];
    const float* nodes = (const float*)d_in[1];
    const float* actor_ctrs = (const float*)d_in[2];
    const float* node_ctrs = (const float*)d_in[3];
    const int* hi = (const int*)d_in[4];
    const int* wi = (const int*)d_in[5];
    const float* Wd1 = (const float*)d_in[6];
    const float* bd1 = (const float*)d_in[7];
    const float* Wd2 = (const float*)d_in[8];
    const float* gnd2_w = (const float*)d_in[9];
    const float* gnd2_b = (const float*)d_in[10];
    const float* Wq = (const float*)d_in[11];
    const float* gnq_w = (const float*)d_in[12];
    const float* gnq_b = (const float*)d_in[13];
    const float* Wc1 = (const float*)d_in[14];
    const float* gnc1_w = (const float*)d_in[15];
    const float* gnc1_b = (const float*)d_in[16];
    const float* Wc2 = (const float*)d_in[17];
    const float* Wa = (const float*)d_in[18];
    const float* gnn_w = (const float*)d_in[19];
    const float* gnn_b = (const float*)d_in[20];
    const float* Wl = (const float*)d_in[21];
    const float* gnl_w = (const float*)d_in[22];
    const float* gnl_b = (const float*)d_in[23];
    float* out = (float*)d_out;

    char* ws = (char*)d_ws;
    unsigned short* wblob = (unsigned short*)ws;  ws += 2 * 16 * 9216 * 2;         // 0.59 MB
    unsigned short* dq = (unsigned short*)ws;     ws += (size_t)150016 * 256 * 2;  // 76.8 MB
    unsigned short* cf2 = (unsigned short*)ws;    ws += (size_t)150016 * 128 * 2;  // 38.4 MB (aliases d0)
    float* ssum = (float*)ws;                     ws += (size_t)M_ACT * DD * 4;    // 2.05 MB
    float* A1 = (float*)ws;                       ws += (size_t)M_ACT * DD * 4;    // 2.05 MB
    int* hist = (int*)ws;                         ws += M_ACT * 4;
    int* offs = (int*)ws;                         ws += (M_ACT + 4) * 4;
    int* cursor = (int*)ws;                       ws += M_ACT * 4;
    int* rank = (int*)ws;                         ws += NE * 4;
    int* ctr4 = (int*)ws;                         ws += 16;
    unsigned short* d0 = cf2;  // alias: d0 consumed by e1 before e2 writes cf2

    hipMemsetAsync(hist, 0, M_ACT * 4, stream);
    hipMemsetAsync(ctr4, 0, 16, stream);
    hist_kernel<<<(NE + 255) / 256, 256, 0, stream>>>(hi, hist);
    scan_kernel<<<1, 256, 0, stream>>>(hist, offs, cursor);
    scatter_kernel<<<(NE + 255) / 256, 256, 0, stream>>>(hi, cursor, rank);
    convert_kernel<<<32, 256, 0, stream>>>(Wd2, Wq, Wc1, Wc2, Wa, Wl, wblob);

    const int AB = (M_ACT + 63) / 64;
    const int D0B = (NE * 32 + 255) / 256;
    // ---- layer 0
    d0_kernel<<<D0B, 256, 0, stream>>>(actor_ctrs, node_ctrs, hi, wi, Wd1, bd1, d0);
    e1_kernel<<<512, 256, 0, stream>>>(actors, d0, Wd2, Wq, gnd2_w, gnd2_b, gnq_w, gnq_b,
                                       hi, dq, &ctr4[0]);
    e2_kernel<<<256, 256, 0, stream>>>(dq, nodes, wi, Wc1, wblob + 10 * 9216,
                                       gnc1_w, gnc1_b, rank, cf2, &ctr4[1]);
    ssum_kernel<<<(M_ACT * 64) / 256, 256, 0, stream>>>(cf2, offs, ssum);
    actor_kernel<<<AB, 256, 0, stream>>>(actors, ssum, gnn_w, gnn_b, gnl_w, gnl_b, wblob, A1);
    // ---- layer 1
    d0_kernel<<<D0B, 256, 0, stream>>>(actor_ctrs, node_ctrs, hi, wi, Wd1 + 256, bd1 + 128, d0);
    e1_kernel<<<512, 256, 0, stream>>>(A1, d0, Wd2 + 16384, Wq + 16384, gnd2_w + 128,
                                       gnd2_b + 128, gnq_w + 128, gnq_b + 128, hi, dq, &ctr4[2]);
    e2_kernel<<<256, 256, 0, stream>>>(dq, nodes, wi, Wc1 + 49152,
                                       wblob + 16 * 9216 + 10 * 9216, gnc1_w + 128,
                                       gnc1_b + 128, rank, cf2, &ctr4[3]);
    ssum_kernel<<<(M_ACT * 64) / 256, 256, 0, stream>>>(cf2, offs, ssum);
    actor_kernel<<<AB, 256, 0, stream>>>(A1, ssum, gnn_w + 128, gnn_b + 128, gnl_w + 128,
                                         gnl_b + 128, wblob + 16 * 9216, out);
}

// Round 3
// 427.740 us; speedup vs baseline: 1.8879x; 1.8879x over previous
//
#include <hip/hip_runtime.h>

#define M_ACT 4000
#define NNODE 20000
#define NE 150000
#define DD 128
#define NT_E 586   // ceil(NE/256), edge kernel: 256 rank-rows per tile
#define ASTR 136   // actor LDS row stride (shorts)
#define WSTR 72    // wblob chunk row stride (shorts)
#define BSTR 136   // transpose buffer row stride (shorts): 68 words == 4 mod 32 -> conflict-free b128

typedef __attribute__((ext_vector_type(8))) short bh8;
typedef __attribute__((ext_vector_type(4))) float vf4;

#define MFMA16(a, b, c) __builtin_amdgcn_mfma_f32_16x16x32_bf16((a), (b), (c), 0, 0, 0)
#define LGKM0() __asm__ volatile("s_waitcnt lgkmcnt(0)" ::: "memory")

__device__ __forceinline__ unsigned short f2bf(float f) {
    unsigned u = __float_as_uint(f);
    u = (u + 0x7fffu + ((u >> 16) & 1u)) >> 16;
    return (unsigned short)u;
}
__device__ __forceinline__ float bf2f(unsigned short s) {
    return __uint_as_float(((unsigned)s) << 16);
}

// GroupNorm stats from one 16x128 MFMA C-layout row-tile (8 col-tiles).
__device__ __forceinline__ void gn_stats8(const vf4* acc, float* mean, float* rs) {
    float s[4], q[4];
#pragma unroll
    for (int i = 0; i < 4; i++) {
        float a = 0.f, b = 0.f;
#pragma unroll
        for (int t = 0; t < 8; t++) { float v = acc[t][i]; a += v; b += v * v; }
        s[i] = a; q[i] = b;
    }
#pragma unroll
    for (int m = 1; m < 16; m <<= 1) {
#pragma unroll
        for (int i = 0; i < 4; i++) {
            s[i] += __shfl_xor(s[i], m, 64);
            q[i] += __shfl_xor(q[i], m, 64);
        }
    }
#pragma unroll
    for (int i = 0; i < 4; i++) {
        float mu = s[i] * (1.0f / 128.0f);
        float var = q[i] * (1.0f / 128.0f) - mu * mu;
        mean[i] = mu;
        rs[i] = rsqrtf(var + 1e-5f);
    }
}

template <bool RELU>
__device__ __forceinline__ void gn_to_lds(const vf4* acc, const float* __restrict__ gw,
                                          const float* __restrict__ gb, unsigned short* sm,
                                          int stride, int cb, int r0, int grp, int lm) {
    float mean[4], rs[4];
    gn_stats8(acc, mean, rs);
#pragma unroll
    for (int t = 0; t < 8; t++) {
        int c = 16 * t + lm;
        float w = gw[c], b = gb[c];
#pragma unroll
        for (int i = 0; i < 4; i++) {
            float y = (acc[t][i] - mean[i]) * rs[i] * w + b;
            if (RELU) y = fmaxf(y, 0.0f);
            sm[(r0 + grp * 4 + i) * stride + cb + c] = f2bf(y);
        }
    }
}

__device__ __forceinline__ void load_chunk(const unsigned short* __restrict__ src,
                                           unsigned short* dst, int tid) {
    for (int idx = tid; idx < 1152; idx += 256) {
        *(uint4*)&dst[idx * 8] = *(const uint4*)&src[idx * 8];
    }
}

// =====================  d0 = relu(ctr_d @ Wd1^T + b), rank space  =============
__global__ __launch_bounds__(256) void d0_kernel(const float* __restrict__ actor_ctrs,
                                                 const float* __restrict__ node_ctrs,
                                                 const int* __restrict__ hi_s,
                                                 const int* __restrict__ wi_s,
                                                 const float* __restrict__ Wd1,
                                                 const float* __restrict__ bd1,
                                                 unsigned short* __restrict__ d0r) {
    int gid = blockIdx.x * 256 + threadIdx.x;
    int j = gid >> 5;
    if (j >= NE) return;
    int c0 = (gid & 31) * 4;
    int h = hi_s[j], w = wi_s[j];
    float cx = actor_ctrs[h * 2 + 0] - node_ctrs[w * 2 + 0];
    float cy = actor_ctrs[h * 2 + 1] - node_ctrs[w * 2 + 1];
    unsigned short r[4];
#pragma unroll
    for (int k = 0; k < 4; k++) {
        int c = c0 + k;
        float v = fmaf(cy, Wd1[c * 2 + 1], fmaf(cx, Wd1[c * 2 + 0], bd1[c]));
        r[k] = f2bf(fmaxf(v, 0.f));
    }
    unsigned lo = (unsigned)r[0] | ((unsigned)r[1] << 16);
    unsigned hi2 = (unsigned)r[2] | ((unsigned)r[3] << 16);
    *(uint2*)&d0r[(size_t)j * DD + c0] = make_uint2(lo, hi2);
}

// =====================  Q2 = relu(gn(agts@Wq^T)) @ Wc1_q^T  (M-level)  ========
__global__ __launch_bounds__(256, 2) void q2_kernel(const float* __restrict__ agts,
                                                    const unsigned short* __restrict__ wblob_l,
                                                    const float* __restrict__ gnq_w,
                                                    const float* __restrict__ gnq_b,
                                                    float* __restrict__ Q2) {
    __shared__ unsigned short smA[64 * ASTR];
    __shared__ unsigned short smW[128 * WSTR];
    const int tid = threadIdx.x;
    const int wave = tid >> 6, lane = tid & 63, grp = lane >> 4, lm = lane & 15;
    const int m0 = blockIdx.x * 64;
    const int r0 = wave * 16;
    const int arow = r0 + lm;

    for (int idx = tid; idx < 64 * 32; idx += 256) {
        int r = idx >> 5, q = idx & 31;
        int m = m0 + r;
        if (m >= M_ACT) m = 0;
        const float4 v = *(const float4*)(agts + (size_t)m * DD + q * 4);
        unsigned lo = (unsigned)f2bf(v.x) | ((unsigned)f2bf(v.y) << 16);
        unsigned hi2 = (unsigned)f2bf(v.z) | ((unsigned)f2bf(v.w) << 16);
        *(uint2*)&smA[r * ASTR + q * 4] = make_uint2(lo, hi2);
    }
    __syncthreads();

    vf4 acc[8];
#pragma unroll
    for (int t = 0; t < 8; t++) acc[t] = (vf4){0.f, 0.f, 0.f, 0.f};
    for (int ch = 0; ch < 2; ch++) {
        load_chunk(wblob_l + (2 + ch) * 9216, smW, tid);
        __syncthreads();
#pragma unroll
        for (int k0 = 0; k0 < 64; k0 += 32) {
            bh8 a = *(const bh8*)&smA[arow * ASTR + ch * 64 + k0 + grp * 8];
#pragma unroll
            for (int t = 0; t < 8; t++) {
                bh8 b = *(const bh8*)&smW[(16 * t + lm) * WSTR + k0 + grp * 8];
                acc[t] = MFMA16(a, b, acc[t]);
            }
        }
        __syncthreads();
    }
    gn_to_lds<true>(acc, gnq_w, gnq_b, smA, ASTR, 0, r0, grp, lm);

#pragma unroll
    for (int t = 0; t < 8; t++) acc[t] = (vf4){0.f, 0.f, 0.f, 0.f};
    for (int ch = 0; ch < 2; ch++) {
        load_chunk(wblob_l + (6 + ch) * 9216, smW, tid);
        __syncthreads();
#pragma unroll
        for (int k0 = 0; k0 < 64; k0 += 32) {
            bh8 a = *(const bh8*)&smA[arow * ASTR + ch * 64 + k0 + grp * 8];
#pragma unroll
            for (int t = 0; t < 8; t++) {
                bh8 b = *(const bh8*)&smW[(16 * t + lm) * WSTR + k0 + grp * 8];
                acc[t] = MFMA16(a, b, acc[t]);
            }
        }
        __syncthreads();
    }
#pragma unroll
    for (int t = 0; t < 8; t++) {
        int c = 16 * t + lm;
#pragma unroll
        for (int i = 0; i < 4; i++) {
            int m = m0 + r0 + grp * 4 + i;
            if (m < M_ACT) Q2[(size_t)m * DD + c] = acc[t][i];
        }
    }
}

// =====================  N2 = nodes @ Wc1_n^T  (N-level)  ======================
__global__ __launch_bounds__(256, 2) void n2_kernel(const float* __restrict__ nodes,
                                                    const unsigned short* __restrict__ wblob_l,
                                                    float* __restrict__ N2) {
    __shared__ unsigned short smA[64 * ASTR];
    __shared__ unsigned short smW[128 * WSTR];
    const int tid = threadIdx.x;
    const int wave = tid >> 6, lane = tid & 63, grp = lane >> 4, lm = lane & 15;
    const int n0 = blockIdx.x * 64;
    const int r0 = wave * 16;
    const int arow = r0 + lm;

    for (int idx = tid; idx < 64 * 32; idx += 256) {
        int r = idx >> 5, q = idx & 31;
        int n = n0 + r;
        if (n >= NNODE) n = 0;
        const float4 v = *(const float4*)(nodes + (size_t)n * DD + q * 4);
        unsigned lo = (unsigned)f2bf(v.x) | ((unsigned)f2bf(v.y) << 16);
        unsigned hi2 = (unsigned)f2bf(v.z) | ((unsigned)f2bf(v.w) << 16);
        *(uint2*)&smA[r * ASTR + q * 4] = make_uint2(lo, hi2);
    }
    __syncthreads();

    vf4 acc[8];
#pragma unroll
    for (int t = 0; t < 8; t++) acc[t] = (vf4){0.f, 0.f, 0.f, 0.f};
    for (int ch = 0; ch < 2; ch++) {
        load_chunk(wblob_l + (8 + ch) * 9216, smW, tid);
        __syncthreads();
#pragma unroll
        for (int k0 = 0; k0 < 64; k0 += 32) {
            bh8 a = *(const bh8*)&smA[arow * ASTR + ch * 64 + k0 + grp * 8];
#pragma unroll
            for (int t = 0; t < 8; t++) {
                bh8 b = *(const bh8*)&smW[(16 * t + lm) * WSTR + k0 + grp * 8];
                acc[t] = MFMA16(a, b, acc[t]);
            }
        }
        __syncthreads();
    }
#pragma unroll
    for (int t = 0; t < 8; t++) {
        int c = 16 * t + lm;
#pragma unroll
        for (int i = 0; i < 4; i++) {
            int n = n0 + r0 + grp * 4 + i;
            if (n < NNODE) N2[(size_t)n * DD + c] = acc[t][i];
        }
    }
}

// =====================  EDGE KERNEL (persistent, rank space)  =================
// cf2[j] = (relu(gn(d(j)@Wc1_d^T + Q2[hi_s[j]] + N2[wi_s[j]], gnc1))) @ Wc2^T
// where d(j) = relu(gn(d0r[j] @ Wd2^T, gnd2)).
__global__ __launch_bounds__(512, 2) void edge_kernel(
    const unsigned short* __restrict__ d0r, const float* __restrict__ Q2,
    const float* __restrict__ N2, const int* __restrict__ hi_s,
    const int* __restrict__ wi_s, const unsigned short* __restrict__ wblob_l,
    const float* __restrict__ gnd2_w, const float* __restrict__ gnd2_b,
    const float* __restrict__ gnc1_w, const float* __restrict__ gnc1_b,
    unsigned short* __restrict__ cf2, int* __restrict__ ctr) {
    __shared__ unsigned short smW[4 * 9216];     // Wd2 k0,k1 | Wc1_d k0,k1
    __shared__ unsigned short smBuf[8][32 * BSTR];
    __shared__ int smTile;
    {
        const int src0[4] = {0, 1, 4, 5};
#pragma unroll
        for (int s = 0; s < 4; s++)
            for (int idx = threadIdx.x; idx < 1152; idx += 512)
                *(uint4*)&smW[s * 9216 + idx * 8] =
                    *(const uint4*)&wblob_l[src0[s] * 9216 + idx * 8];
    }
    const int wave = threadIdx.x >> 6, lane = threadIdx.x & 63;
    const int grp = lane >> 4, lm = lane & 15;
    unsigned short* buf = smBuf[wave];
    const unsigned short* w2 = wblob_l + 10 * 9216;  // Wc2, L2-hot

    while (true) {
        __syncthreads();
        if (threadIdx.x == 0) smTile = atomicAdd(ctr, 1);
        __syncthreads();
        int tile = smTile;
        if (tile >= NT_E) break;
        int j0 = tile * 256 + wave * 32;
        if (j0 >= NE) continue;

        vf4 acc[2][8];
        // prefetch A1 frags (global, streaming) + gather indices
        bh8 a1[2][4];
        int hg[2][4], wg[2][4];
#pragma unroll
        for (int rt = 0; rt < 2; rt++) {
            int r = j0 + rt * 16 + lm;
            if (r > NE - 1) r = NE - 1;
#pragma unroll
            for (int ks = 0; ks < 4; ks++)
                a1[rt][ks] = *(const bh8*)&d0r[(size_t)r * DD + ks * 32 + grp * 8];
#pragma unroll
            for (int i = 0; i < 4; i++) {
                int j = j0 + rt * 16 + grp * 4 + i;
                if (j > NE - 1) j = NE - 1;
                hg[rt][i] = hi_s[j];
                wg[rt][i] = wi_s[j];
            }
        }
        // ---- GEMM1: d0 @ Wd2^T
#pragma unroll
        for (int rt = 0; rt < 2; rt++)
#pragma unroll
            for (int t = 0; t < 8; t++) acc[rt][t] = (vf4){0.f, 0.f, 0.f, 0.f};
#pragma unroll
        for (int ks = 0; ks < 4; ks++) {
            bh8 B[8];
#pragma unroll
            for (int t = 0; t < 8; t++)
                B[t] = *(const bh8*)&smW[(ks >> 1) * 9216 + (16 * t + lm) * WSTR +
                                         (ks & 1) * 32 + grp * 8];
#pragma unroll
            for (int rt = 0; rt < 2; rt++)
#pragma unroll
                for (int t = 0; t < 8; t++) acc[rt][t] = MFMA16(a1[rt][ks], B[t], acc[rt][t]);
        }
        LGKM0();
#pragma unroll
        for (int rt = 0; rt < 2; rt++) {
            float mean[4], rs[4];
            gn_stats8(acc[rt], mean, rs);
#pragma unroll
            for (int t = 0; t < 8; t++) {
                int c = 16 * t + lm;
                float w = gnd2_w[c], b = gnd2_b[c];
#pragma unroll
                for (int i = 0; i < 4; i++) {
                    float y = (acc[rt][t][i] - mean[i]) * rs[i] * w + b;
                    buf[(rt * 16 + grp * 4 + i) * BSTR + c] = f2bf(fmaxf(y, 0.f));
                }
            }
        }
        LGKM0();
        // ---- GEMM2: d @ Wc1_d^T
#pragma unroll
        for (int rt = 0; rt < 2; rt++)
#pragma unroll
            for (int t = 0; t < 8; t++) acc[rt][t] = (vf4){0.f, 0.f, 0.f, 0.f};
#pragma unroll
        for (int ks = 0; ks < 4; ks++) {
            bh8 B[8];
#pragma unroll
            for (int t = 0; t < 8; t++)
                B[t] = *(const bh8*)&smW[(2 + (ks >> 1)) * 9216 + (16 * t + lm) * WSTR +
                                         (ks & 1) * 32 + grp * 8];
#pragma unroll
            for (int rt = 0; rt < 2; rt++) {
                bh8 a = *(const bh8*)&buf[(rt * 16 + lm) * BSTR + ks * 32 + grp * 8];
#pragma unroll
                for (int t = 0; t < 8; t++) acc[rt][t] = MFMA16(a, B[t], acc[rt][t]);
            }
        }
        // ---- add Q2[hi]+N2[wi], gn(c1)+relu -> buf
#pragma unroll
        for (int rt = 0; rt < 2; rt++)
#pragma unroll
            for (int t = 0; t < 8; t++) {
                int c = 16 * t + lm;
#pragma unroll
                for (int i = 0; i < 4; i++)
                    acc[rt][t][i] +=
                        Q2[(size_t)hg[rt][i] * DD + c] + N2[(size_t)wg[rt][i] * DD + c];
            }
        LGKM0();
#pragma unroll
        for (int rt = 0; rt < 2; rt++) {
            float mean[4], rs[4];
            gn_stats8(acc[rt], mean, rs);
#pragma unroll
            for (int t = 0; t < 8; t++) {
                int c = 16 * t + lm;
                float w = gnc1_w[c], b = gnc1_b[c];
#pragma unroll
                for (int i = 0; i < 4; i++) {
                    float y = (acc[rt][t][i] - mean[i]) * rs[i] * w + b;
                    buf[(rt * 16 + grp * 4 + i) * BSTR + c] = f2bf(fmaxf(y, 0.f));
                }
            }
        }
        LGKM0();
        // ---- GEMM3: cf1 @ Wc2^T (B streamed from L2-hot blob)
#pragma unroll
        for (int rt = 0; rt < 2; rt++)
#pragma unroll
            for (int t = 0; t < 8; t++) acc[rt][t] = (vf4){0.f, 0.f, 0.f, 0.f};
#pragma unroll
        for (int ks = 0; ks < 4; ks++) {
            bh8 B[8];
#pragma unroll
            for (int t = 0; t < 8; t++)
                B[t] = *(const bh8*)&w2[(ks >> 1) * 9216 + (16 * t + lm) * WSTR +
                                        (ks & 1) * 32 + grp * 8];
#pragma unroll
            for (int rt = 0; rt < 2; rt++) {
                bh8 a = *(const bh8*)&buf[(rt * 16 + lm) * BSTR + ks * 32 + grp * 8];
#pragma unroll
                for (int t = 0; t < 8; t++) acc[rt][t] = MFMA16(a, B[t], acc[rt][t]);
            }
        }
        // ---- pack to buf, coalesced uint4 store (rank space => contiguous rows)
        LGKM0();
#pragma unroll
        for (int rt = 0; rt < 2; rt++)
#pragma unroll
            for (int t = 0; t < 8; t++) {
                int c = 16 * t + lm;
#pragma unroll
                for (int i = 0; i < 4; i++)
                    buf[(rt * 16 + grp * 4 + i) * BSTR + c] = f2bf(acc[rt][t][i]);
            }
        LGKM0();
#pragma unroll
        for (int k = 0; k < 8; k++) {
            int u = lane + 64 * k;  // 0..511 -> 32 rows x 16 segs
            int row = u >> 4, seg = u & 15;
            int j = j0 + row;
            if (j < NE)
                *(uint4*)&cf2[(size_t)j * DD + seg * 8] = *(const uint4*)&buf[row * BSTR + seg * 8];
        }
    }
}

// =====================  SEGMENTED SUM (contiguous rank-space cf2)  ============
__global__ __launch_bounds__(256) void ssum_kernel(const unsigned short* __restrict__ cf2,
                                                   const int* __restrict__ offs,
                                                   float* __restrict__ ssum) {
    int wid = (blockIdx.x * 256 + threadIdx.x) >> 6;
    int lane = threadIdx.x & 63;
    if (wid >= M_ACT) return;
    float s0 = 0.f, s1 = 0.f;
    int j1 = offs[wid + 1];
    for (int j = offs[wid]; j < j1; j++) {
        unsigned u = *(const unsigned*)&cf2[(size_t)j * DD + lane * 2];
        s0 += bf2f((unsigned short)(u & 0xffffu));
        s1 += bf2f((unsigned short)(u >> 16));
    }
    *(float2*)&ssum[(size_t)wid * DD + lane * 2] = make_float2(s0, s1);
}

// =====================  ACTOR KERNEL  =====================
__global__ __launch_bounds__(256, 2) void actor_kernel(
    const float* __restrict__ agts, const float* __restrict__ ssum,
    const float* __restrict__ gnn_w, const float* __restrict__ gnn_b,
    const float* __restrict__ gnl_w, const float* __restrict__ gnl_b,
    const unsigned short* __restrict__ wblob_l, float* __restrict__ dst) {
    __shared__ unsigned short smA[64 * ASTR];
    __shared__ unsigned short smW[128 * WSTR];
    const int tid = threadIdx.x;
    const int wave = tid >> 6, lane = tid & 63, grp = lane >> 4, lm = lane & 15;
    const int m0 = blockIdx.x * 64;
    const int r0 = wave * 16;
    const int arow = r0 + lm;

    for (int idx = tid; idx < 64 * 32; idx += 256) {
        int r = idx >> 5, q = idx & 31;
        int m = m0 + r;
        if (m >= M_ACT) m = 0;
        const float4 v = *(const float4*)(agts + (size_t)m * DD + q * 4);
        unsigned lo = (unsigned)f2bf(v.x) | ((unsigned)f2bf(v.y) << 16);
        unsigned hi2 = (unsigned)f2bf(v.z) | ((unsigned)f2bf(v.w) << 16);
        *(uint2*)&smA[r * ASTR + q * 4] = make_uint2(lo, hi2);
    }
    __syncthreads();

    vf4 acc[8];
#pragma unroll
    for (int t = 0; t < 8; t++) acc[t] = (vf4){0.f, 0.f, 0.f, 0.f};
    for (int ch = 0; ch < 2; ch++) {
        load_chunk(wblob_l + (12 + ch) * 9216, smW, tid);
        __syncthreads();
#pragma unroll
        for (int k0 = 0; k0 < 64; k0 += 32) {
            bh8 a = *(const bh8*)&smA[arow * ASTR + ch * 64 + k0 + grp * 8];
#pragma unroll
            for (int t = 0; t < 8; t++) {
                bh8 b = *(const bh8*)&smW[(16 * t + lm) * WSTR + k0 + grp * 8];
                acc[t] = MFMA16(a, b, acc[t]);
            }
        }
        __syncthreads();
    }
#pragma unroll
    for (int t = 0; t < 8; t++) {
#pragma unroll
        for (int i = 0; i < 4; i++) {
            int m = m0 + r0 + grp * 4 + i;
            if (m < M_ACT) acc[t][i] += ssum[(size_t)m * DD + 16 * t + lm];
        }
    }
    gn_to_lds<true>(acc, gnn_w, gnn_b, smA, ASTR, 0, r0, grp, lm);

#pragma unroll
    for (int t = 0; t < 8; t++) acc[t] = (vf4){0.f, 0.f, 0.f, 0.f};
    for (int ch = 0; ch < 2; ch++) {
        load_chunk(wblob_l + (14 + ch) * 9216, smW, tid);
        __syncthreads();
#pragma unroll
        for (int k0 = 0; k0 < 64; k0 += 32) {
            bh8 a = *(const bh8*)&smA[arow * ASTR + ch * 64 + k0 + grp * 8];
#pragma unroll
            for (int t = 0; t < 8; t++) {
                bh8 b = *(const bh8*)&smW[(16 * t + lm) * WSTR + k0 + grp * 8];
                acc[t] = MFMA16(a, b, acc[t]);
            }
        }
        __syncthreads();
    }
    {
        float mean[4], rs[4];
        gn_stats8(acc, mean, rs);
#pragma unroll
        for (int t = 0; t < 8; t++) {
            int c = 16 * t + lm;
            float w = gnl_w[c], b = gnl_b[c];
#pragma unroll
            for (int i = 0; i < 4; i++) {
                int m = m0 + r0 + grp * 4 + i;
                if (m < M_ACT) {
                    float y = (acc[t][i] - mean[i]) * rs[i] * w + b;
                    y += agts[(size_t)m * DD + c];
                    dst[(size_t)m * DD + c] = fmaxf(y, 0.f);
                }
            }
        }
    }
}

// =====================  SETUP KERNELS  =====================
__global__ void hist_kernel(const int* __restrict__ hi, int* __restrict__ hist) {
    int e = blockIdx.x * 256 + threadIdx.x;
    if (e < NE) atomicAdd(&hist[hi[e]], 1);
}

__global__ void scan_kernel(const int* __restrict__ hist, int* __restrict__ offs,
                            int* __restrict__ cursor) {
    __shared__ int part[256];
    int t = threadIdx.x;
    int base = t * 16;
    int s = 0;
    if (base < M_ACT)
        for (int i = 0; i < 16; i++) s += hist[base + i];
    part[t] = s;
    __syncthreads();
    for (int d = 1; d < 256; d <<= 1) {
        int u = (t >= d) ? part[t - d] : 0;
        __syncthreads();
        part[t] += u;
        __syncthreads();
    }
    int excl = part[t] - s;
    if (base < M_ACT) {
        int run = excl;
        for (int i = 0; i < 16; i++) {
            offs[base + i] = run;
            cursor[base + i] = run;
            run += hist[base + i];
        }
        if (base + 16 == M_ACT) offs[M_ACT] = run;
    }
}

__global__ void scatter_kernel(const int* __restrict__ hi, const int* __restrict__ wi,
                               int* __restrict__ cursor, int* __restrict__ hi_s,
                               int* __restrict__ wi_s) {
    int e = blockIdx.x * 256 + threadIdx.x;
    if (e < NE) {
        int h = hi[e];
        int p = atomicAdd(&cursor[h], 1);
        hi_s[p] = h;
        wi_s[p] = wi[e];
    }
}

__global__ void convert_kernel(const float* __restrict__ Wd2, const float* __restrict__ Wq,
                               const float* __restrict__ Wc1, const float* __restrict__ Wc2,
                               const float* __restrict__ Wa, const float* __restrict__ Wl,
                               unsigned short* __restrict__ wblob) {
    int ci = blockIdx.x;  // 0..31
    int l = ci >> 4, r = ci & 15;
    const float* src;
    int kc, K;
    if (r < 2)       { src = Wd2 + l * 16384; kc = r;      K = 128; }
    else if (r < 4)  { src = Wq  + l * 16384; kc = r - 2;  K = 128; }
    else if (r < 10) { src = Wc1 + l * 49152; kc = r - 4;  K = 384; }
    else if (r < 12) { src = Wc2 + l * 16384; kc = r - 10; K = 128; }
    else if (r < 14) { src = Wa  + l * 16384; kc = r - 12; K = 128; }
    else             { src = Wl  + l * 16384; kc = r - 14; K = 128; }
    unsigned short* dst = wblob + (size_t)ci * 9216;
    for (int idx = threadIdx.x; idx < 9216; idx += 256) {
        int n = idx / 72, kk = idx - n * 72;
        float v = (kk < 64) ? src[n * K + kc * 64 + kk] : 0.f;
        dst[idx] = f2bf(v);
    }
}

extern "C" void kernel_launch(void* const* d_in, const int* in_sizes, int n_in,
                              void* d_out, int out_size, void* d_ws, size_t ws_size,
                              hipStream_t stream) {
    const float* actors = (const float*)d_in[0];
    const float* nodes = (const float*)d_in[1];
    const float* actor_ctrs = (const float*)d_in[2];
    const float* node_ctrs = (const float*)d_in[3];
    const int* hi = (const int*)d_in[4];
    const int* wi = (const int*)d_in[5];
    const float* Wd1 = (const float*)d_in[6];
    const float* bd1 = (const float*)d_in[7];
    const float* Wd2 = (const float*)d_in[8];
    const float* gnd2_w = (const float*)d_in[9];
    const float* gnd2_b = (const float*)d_in[10];
    const float* Wq = (const float*)d_in[11];
    const float* gnq_w = (const float*)d_in[12];
    const float* gnq_b = (const float*)d_in[13];
    const float* Wc1 = (const float*)d_in[14];
    const float* gnc1_w = (const float*)d_in[15];
    const float* gnc1_b = (const float*)d_in[16];
    const float* Wc2 = (const float*)d_in[17];
    const float* Wa = (const float*)d_in[18];
    const float* gnn_w = (const float*)d_in[19];
    const float* gnn_b = (const float*)d_in[20];
    const float* Wl = (const float*)d_in[21];
    const float* gnl_w = (const float*)d_in[22];
    const float* gnl_b = (const float*)d_in[23];
    float* out = (float*)d_out;

    char* ws = (char*)d_ws;
    unsigned short* wblob = (unsigned short*)ws;  ws += 2 * 16 * 9216 * 2;       // 0.59 MB
    unsigned short* d0r = (unsigned short*)ws;    ws += (size_t)150016 * DD * 2; // 38.4 MB
    unsigned short* cf2 = (unsigned short*)ws;    ws += (size_t)150016 * DD * 2; // 38.4 MB
    float* Q2 = (float*)ws;                       ws += (size_t)M_ACT * DD * 4;  // 2.05 MB
    float* N2_0 = (float*)ws;                     ws += (size_t)NNODE * DD * 4;  // 10.24 MB
    float* N2_1 = (float*)ws;                     ws += (size_t)NNODE * DD * 4;  // 10.24 MB
    float* ssum = (float*)ws;                     ws += (size_t)M_ACT * DD * 4;  // 2.05 MB
    float* A1 = (float*)ws;                       ws += (size_t)M_ACT * DD * 4;  // 2.05 MB
    int* hist = (int*)ws;                         ws += M_ACT * 4;
    int* offs = (int*)ws;                         ws += (M_ACT + 4) * 4;
    int* cursor = (int*)ws;                       ws += M_ACT * 4;
    int* hi_s = (int*)ws;                         ws += NE * 4;
    int* wi_s = (int*)ws;                         ws += NE * 4;
    int* ctr4 = (int*)ws;                         ws += 16;

    hipMemsetAsync(hist, 0, M_ACT * 4, stream);
    hipMemsetAsync(ctr4, 0, 16, stream);
    hist_kernel<<<(NE + 255) / 256, 256, 0, stream>>>(hi, hist);
    scan_kernel<<<1, 256, 0, stream>>>(hist, offs, cursor);
    scatter_kernel<<<(NE + 255) / 256, 256, 0, stream>>>(hi, wi, cursor, hi_s, wi_s);
    convert_kernel<<<32, 256, 0, stream>>>(Wd2, Wq, Wc1, Wc2, Wa, Wl, wblob);

    const unsigned short* wb0 = wblob;
    const unsigned short* wb1 = wblob + 16 * 9216;
    const int AB = (M_ACT + 63) / 64;      // 63
    const int NB = (NNODE + 63) / 64;      // 313
    const int D0B = (NE * 32 + 255) / 256;

    n2_kernel<<<NB, 256, 0, stream>>>(nodes, wb0, N2_0);
    n2_kernel<<<NB, 256, 0, stream>>>(nodes, wb1, N2_1);

    // ---- layer 0
    d0_kernel<<<D0B, 256, 0, stream>>>(actor_ctrs, node_ctrs, hi_s, wi_s, Wd1, bd1, d0r);
    q2_kernel<<<AB, 256, 0, stream>>>(actors, wb0, gnq_w, gnq_b, Q2);
    edge_kernel<<<256, 512, 0, stream>>>(d0r, Q2, N2_0, hi_s, wi_s, wb0, gnd2_w, gnd2_b,
                                         gnc1_w, gnc1_b, cf2, &ctr4[0]);
    ssum_kernel<<<(M_ACT * 64) / 256, 256, 0, stream>>>(cf2, offs, ssum);
    actor_kernel<<<AB, 256, 0, stream>>>(actors, ssum, gnn_w, gnn_b, gnl_w, gnl_b, wb0, A1);
    // ---- layer 1
    d0_kernel<<<D0B, 256, 0, stream>>>(actor_ctrs, node_ctrs, hi_s, wi_s, Wd1 + 256, bd1 + 128,
                                       d0r);
    q2_kernel<<<AB, 256, 0, stream>>>(A1, wb1, gnq_w + 128, gnq_b + 128, Q2);
    edge_kernel<<<256, 512, 0, stream>>>(d0r, Q2, N2_1, hi_s, wi_s, wb1, gnd2_w + 128,
                                         gnd2_b + 128, gnc1_w + 128, gnc1_b + 128, cf2,
                                         &ctr4[1]);
    ssum_kernel<<<(M_ACT * 64) / 256, 256, 0, stream>>>(cf2, offs, ssum);
    actor_kernel<<<AB, 256, 0, stream>>>(A1, ssum, gnn_w + 128, gnn_b + 128, gnl_w + 128,
                                         gnl_b + 128, wb1, out);
}